// Round 13
// baseline (774.517 us; speedup 1.0000x reference)
//
#include <hip/hip_runtime.h>
#include <hip/hip_bf16.h>
#include <stdint.h>

#define N_NODES 100000
#define N_EDGES 1638400
#define IN_FEAT 128
#define OUT_FEAT 64
#define NUM_RELS 8
#define NTILES ((N_NODES + 63) / 64)          // 1563
#define TGRID 1024                            // persistent transform blocks (4/CU)

#define BUCKET_BITS 9
#define BUCKET_SIZE 512                       // nodes per bucket
#define NBUCKETS ((N_NODES + BUCKET_SIZE - 1) / BUCKET_SIZE)   // 196
#define BCAP 8960                             // fixed bucket capacity (max cnt ~8663 = mean 8389 + 3sigma)
#define ABLOCKS 200
#define AEDGES (N_EDGES / ABLOCKS)            // 8192 edges per bin block
#define APT (AEDGES / 1024)                   // 8 edges per thread

#define GB_HALF 256                           // nodes per gather block (half bucket)
#define GPAD 68                               // padded acc row stride in floats (272B: 16B-aligned, bank-spread)

// packed edge: src [0:16], rel [17:19], local-dst [20:28]
typedef __attribute__((ext_vector_type(8))) short short8;
typedef __attribute__((ext_vector_type(4))) float floatx4;

__device__ __forceinline__ unsigned short f2bf(float x) {
    union { float f; uint32_t u; } c; c.f = x;
    uint32_t u = c.u;
    u += 0x7FFFu + ((u >> 16) & 1u);   // RNE
    return (unsigned short)(u >> 16);
}

// pack 2 f32 -> u32 of 2 bf16 (RNE), single HW instr; no builtin on gfx950
__device__ __forceinline__ uint32_t cvt_pk_bf16(float lo, float hi) {
    uint32_t r;
    asm("v_cvt_pk_bf16_f32 %0, %1, %2" : "=v"(r) : "v"(lo), "v"(hi));
    return r;
}

#define W8 (NUM_RELS * OUT_FEAT * IN_FEAT / 8)   // 8192 short8 units

// ---------------- A1: single-pass bin + W-convert rider ----------------------
// bucket b owns bins[b*BCAP .. b*BCAP+BCAP); per-block LDS counts -> one
// global cursor bump per bucket -> scatter (UNSORTED within bucket -- the
// LDS-accumulate gather no longer needs per-node sorting). Blocks 0..7 also
// convert W to bf16. Cursors zeroed by stream-ordered hipMemsetAsync.
__global__ __launch_bounds__(1024)
void bin_kernel(const int* __restrict__ src, const int* __restrict__ dst,
                const int* __restrict__ typ, int* __restrict__ bucketCursor,
                uint32_t* __restrict__ bins,
                const float* __restrict__ W, unsigned short* __restrict__ W_bf) {
    const int t = threadIdx.x;
    if (blockIdx.x < 8) {                      // W-convert rider: 8*1024 = 8192 units
        int w = blockIdx.x * 1024 + t;
        const float* s = W + (size_t)w * 8;
        float4 a = *(const float4*)s, b = *(const float4*)(s + 4);
        short8 v;
        v[0] = f2bf(a.x); v[1] = f2bf(a.y); v[2] = f2bf(a.z); v[3] = f2bf(a.w);
        v[4] = f2bf(b.x); v[5] = f2bf(b.y); v[6] = f2bf(b.z); v[7] = f2bf(b.w);
        *(short8*)(W_bf + (size_t)w * 8) = v;
    }
    __shared__ int h[NBUCKETS];
    __shared__ int base[NBUCKETS];
    if (t < NBUCKETS) h[t] = 0;
    __syncthreads();
    uint32_t pk[APT]; int bk[APT], rk[APT];
    #pragma unroll
    for (int i = 0; i < APT; ++i) {
        int e = blockIdx.x * AEDGES + i * 1024 + t;
        int d = dst[e];
        int b = d >> BUCKET_BITS;
        bk[i] = b;
        pk[i] = ((uint32_t)(d & (BUCKET_SIZE - 1)) << 20) | ((uint32_t)typ[e] << 17) | (uint32_t)src[e];
        rk[i] = atomicAdd(&h[b], 1);
    }
    __syncthreads();
    if (t < NBUCKETS && h[t] > 0) base[t] = atomicAdd(&bucketCursor[t], h[t]);
    __syncthreads();
    #pragma unroll
    for (int i = 0; i < APT; ++i)
        bins[(size_t)bk[i] * BCAP + base[bk[i]] + rk[i]] = pk[i];
}

// ---------------- transform: R2 champion structure (frozen) ------------------
__global__ __launch_bounds__(512)
void transform_kernel(const float* __restrict__ feat,
                      const unsigned short* __restrict__ W_bf,
                      unsigned short* __restrict__ xw) {
    const int t    = threadIdx.x;
    const int lane = t & 63;
    const int r    = t >> 6;               // wave = relation
    const int quad = lane >> 4;
    const int lrow = lane & 15;

    __shared__ unsigned short sA[2][64 * 136];

    // W-fragments (first operand): rows = channels jm*16+lrow, k-contiguous
    short8 wfr[4][4];
    #pragma unroll
    for (int jm = 0; jm < 4; ++jm)
        #pragma unroll
        for (int kk = 0; kk < 4; ++kk)
            wfr[jm][kk] = *(const short8*)(W_bf +
                ((size_t)r * OUT_FEAT + jm * 16 + lrow) * IN_FEAT + kk * 32 + quad * 8);

    int tile = blockIdx.x;

    // stage first tile into sA[0]
    #pragma unroll
    for (int i = 0; i < 4; ++i) {
        int f4 = t + 512 * i;               // 0..2047
        int row = f4 >> 5, c4 = f4 & 31;
        int n = tile * 64 + row;
        float4 v = (n < N_NODES) ? *(const float4*)(feat + (size_t)n * IN_FEAT + c4 * 4)
                                 : make_float4(0.f, 0.f, 0.f, 0.f);
        uint2 q;
        q.x = cvt_pk_bf16(v.x, v.y);
        q.y = cvt_pk_bf16(v.z, v.w);
        *(uint2*)&sA[0][row * 136 + c4 * 4] = q;
    }

    int p = 0;
    while (tile < NTILES) {
        __syncthreads();                    // sA[p] staged; sA[p^1] fully consumed
        int nxt = tile + TGRID;
        if (nxt < NTILES) {
            #pragma unroll
            for (int i = 0; i < 4; ++i) {
                int f4 = t + 512 * i;
                int row = f4 >> 5, c4 = f4 & 31;
                int n = nxt * 64 + row;
                float4 v = (n < N_NODES) ? *(const float4*)(feat + (size_t)n * IN_FEAT + c4 * 4)
                                         : make_float4(0.f, 0.f, 0.f, 0.f);
                uint2 q;
                q.x = cvt_pk_bf16(v.x, v.y);
                q.y = cvt_pk_bf16(v.z, v.w);
                *(uint2*)&sA[p ^ 1][row * 136 + c4 * 4] = q;
            }
        }

        const int n0 = tile * 64;
        const bool full = (n0 + 64 <= N_NODES);
        #pragma unroll
        for (int nb = 0; nb < 4; ++nb) {
            floatx4 acc[4] = {{0,0,0,0},{0,0,0,0},{0,0,0,0},{0,0,0,0}};
            #pragma unroll
            for (int kk = 0; kk < 4; ++kk) {
                short8 bfrag = *(const short8*)&sA[p][(nb * 16 + lrow) * 136 + kk * 32 + quad * 8];
                #pragma unroll
                for (int jm = 0; jm < 4; ++jm)
                    acc[jm] = __builtin_amdgcn_mfma_f32_16x16x32_bf16(wfr[jm][kk], bfrag, acc[jm], 0, 0, 0);
            }
            int n = n0 + nb * 16 + lrow;
            if (full || n < N_NODES) {
                unsigned short* rowp = xw + ((size_t)r * N_NODES + n) * OUT_FEAT;
                #pragma unroll
                for (int jm = 0; jm < 4; ++jm) {
                    uint2 u;
                    u.x = (uint32_t)f2bf(acc[jm][0]) | ((uint32_t)f2bf(acc[jm][1]) << 16);
                    u.y = (uint32_t)f2bf(acc[jm][2]) | ((uint32_t)f2bf(acc[jm][3]) << 16);
                    *(uint2*)(rowp + jm * 16 + quad * 4) = u;
                }
            }
        }
        p ^= 1;
        tile = nxt;
    }
}

// ---------------- gather: LDS-accumulate over UNSORTED bucket ----------------
// Replaces sortb+CSR-gather: block = half a bucket (256 nodes) with f32
// accumulators in LDS. Scan the bucket's unsorted bin region; for each edge
// belonging to this half, 8 lanes load the 128B xw row (uint4 each) and
// atomicAdd 8 channels into acc[local_dst]. Subgroup = 8 lanes per edge,
// 4 edges in flight. Write-out coalesced float4.
__global__ __launch_bounds__(512)
void gather_kernel(const unsigned short* __restrict__ xw, const int* __restrict__ bucketCursor,
                   const uint32_t* __restrict__ bins, float* __restrict__ out) {
    __shared__ float acc[GB_HALF * GPAD];       // 256*68*4 = 69632 B
    const int t    = threadIdx.x;
    const int b    = blockIdx.x >> 1;
    const int half = blockIdx.x & 1;
    const int sub  = t >> 3;                    // 0..63: edge slot
    const int l    = t & 7;                     // channel octet
    #pragma unroll
    for (int i = 0; i < (GB_HALF * GPAD) / 512; ++i)    // 34 exact
        acc[t + i * 512] = 0.f;
    __syncthreads();

    const int s   = b * BCAP;
    const int cnt = bucketCursor[b];
    const int lo  = half * GB_HALF;
    for (int base = 0; base < cnt; base += 256) {
        uint32_t pk[4];
        #pragma unroll
        for (int u = 0; u < 4; ++u) {
            int idx = base + u * 64 + sub;
            pk[u] = (idx < cnt) ? bins[s + idx] : 0xFFFFFFFFu;   // sentinel ld=4095 -> filtered
        }
        #pragma unroll
        for (int u = 0; u < 4; ++u) {
            int ldl = (int)(pk[u] >> 20) - lo;
            if ((unsigned)ldl < GB_HALF) {
                int rel = (pk[u] >> 17) & 7;
                int src = (int)(pk[u] & 0x1FFFF);
                uint4 v = *(const uint4*)(xw + ((size_t)rel * N_NODES + src) * OUT_FEAT + l * 8);
                float* row = acc + ldl * GPAD + l * 8;
                union { uint32_t u; float f; } c;
                c.u = v.x << 16;         atomicAdd(row + 0, c.f);
                c.u = v.x & 0xFFFF0000u; atomicAdd(row + 1, c.f);
                c.u = v.y << 16;         atomicAdd(row + 2, c.f);
                c.u = v.y & 0xFFFF0000u; atomicAdd(row + 3, c.f);
                c.u = v.z << 16;         atomicAdd(row + 4, c.f);
                c.u = v.z & 0xFFFF0000u; atomicAdd(row + 5, c.f);
                c.u = v.w << 16;         atomicAdd(row + 6, c.f);
                c.u = v.w & 0xFFFF0000u; atomicAdd(row + 7, c.f);
            }
        }
    }
    __syncthreads();

    // write out: 256 rows x 64 ch = 4096 float4 units / 512 thr = 8 iters
    const int nbase = b * BUCKET_SIZE + lo;
    #pragma unroll
    for (int i = 0; i < 8; ++i) {
        int unit = t + i * 512;
        int row = unit >> 4, c4 = unit & 15;
        int node = nbase + row;
        if (node < N_NODES) {
            float4 v = *(const float4*)(acc + row * GPAD + c4 * 4);
            *(float4*)(out + (size_t)node * OUT_FEAT + c4 * 4) = v;
        }
    }
}

extern "C" void kernel_launch(void* const* d_in, const int* in_sizes, int n_in,
                              void* d_out, int out_size, void* d_ws, size_t ws_size,
                              hipStream_t stream) {
    const float* feat = (const float*)d_in[0];
    const float* W    = (const float*)d_in[1];
    const int* esrc   = (const int*)d_in[2];
    const int* edst   = (const int*)d_in[3];
    const int* etyp   = (const int*)d_in[4];
    float* out = (float*)d_out;

    // ws layout (~109.6 MB)
    char* ws = (char*)d_ws;
    size_t ofs = 0;
    unsigned short* xw = (unsigned short*)(ws + ofs);
    ofs += (size_t)NUM_RELS * N_NODES * OUT_FEAT * 2;           // 102,400,000
    unsigned short* W_bf = (unsigned short*)(ws + ofs);
    ofs += (size_t)NUM_RELS * OUT_FEAT * IN_FEAT * 2;           // 131,072
    uint32_t* bins = (uint32_t*)(ws + ofs);
    ofs += (size_t)NBUCKETS * BCAP * 4;                         // 7,024,640
    int* bucketCursor = (int*)(ws + ofs); ofs += 1024;

    hipMemsetAsync(bucketCursor, 0, NBUCKETS * sizeof(int), stream);
    bin_kernel<<<ABLOCKS, 1024, 0, stream>>>(esrc, edst, etyp, bucketCursor, bins, W, W_bf);
    transform_kernel<<<TGRID, 512, 0, stream>>>(feat, W_bf, xw);
    gather_kernel<<<NBUCKETS * 2, 512, 0, stream>>>(xw, bucketCursor, bins, out);
}

// Round 14
// 122.621 us; speedup vs baseline: 6.3164x; 6.3164x over previous
//
#include <hip/hip_runtime.h>
#include <hip/hip_bf16.h>
#include <stdint.h>

#define N_NODES 100000
#define N_EDGES 1638400
#define IN_FEAT 128
#define OUT_FEAT 64
#define NUM_RELS 8
#define NTILES ((N_NODES + 63) / 64)          // 1563
#define TGRID 1024                            // persistent transform blocks (4/CU)

#define BUCKET_BITS 9
#define BUCKET_SIZE 512                       // nodes per bucket
#define NBUCKETS ((N_NODES + BUCKET_SIZE - 1) / BUCKET_SIZE)   // 196
#define BCAP 8960                             // fixed bucket capacity (max cnt ~8663 = mean 8389 + 3sigma)
#define ABLOCKS 200
#define AEDGES (N_EDGES / ABLOCKS)            // 8192 edges per bin block
#define APT (AEDGES / 1024)                   // 8 edges per thread
#define BK 9                                  // sortB: 9*1024 = 9216 >= BCAP -- provably covers

// packed edge: src [0:16], rel [17:19], local-dst [20:28]
typedef __attribute__((ext_vector_type(8))) short short8;
typedef __attribute__((ext_vector_type(4))) float floatx4;

__device__ __forceinline__ unsigned short f2bf(float x) {
    union { float f; uint32_t u; } c; c.f = x;
    uint32_t u = c.u;
    u += 0x7FFFu + ((u >> 16) & 1u);   // RNE
    return (unsigned short)(u >> 16);
}

// pack 2 f32 -> u32 of 2 bf16 (RNE), single HW instr; no builtin on gfx950
__device__ __forceinline__ uint32_t cvt_pk_bf16(float lo, float hi) {
    uint32_t r;
    asm("v_cvt_pk_bf16_f32 %0, %1, %2" : "=v"(r) : "v"(lo), "v"(hi));
    return r;
}

#define W8 (NUM_RELS * OUT_FEAT * IN_FEAT / 8)   // 8192 short8 units

// ---------------- A1: single-pass bin + W-convert rider ----------------------
// bucket b owns bins[b*BCAP .. b*BCAP+BCAP); per-block LDS counts -> one
// global cursor bump per bucket -> scatter. Blocks 0..7 additionally convert
// W to bf16 (consumed only by transform, launched later). Cursors are zeroed
// by a stream-ordered hipMemsetAsync before this kernel.
__global__ __launch_bounds__(1024)
void bin_kernel(const int* __restrict__ src, const int* __restrict__ dst,
                const int* __restrict__ typ, int* __restrict__ bucketCursor,
                uint32_t* __restrict__ bins,
                const float* __restrict__ W, unsigned short* __restrict__ W_bf) {
    const int t = threadIdx.x;
    if (blockIdx.x < 8) {                      // W-convert rider: 8*1024 = 8192 units
        int w = blockIdx.x * 1024 + t;
        const float* s = W + (size_t)w * 8;
        float4 a = *(const float4*)s, b = *(const float4*)(s + 4);
        short8 v;
        v[0] = f2bf(a.x); v[1] = f2bf(a.y); v[2] = f2bf(a.z); v[3] = f2bf(a.w);
        v[4] = f2bf(b.x); v[5] = f2bf(b.y); v[6] = f2bf(b.z); v[7] = f2bf(b.w);
        *(short8*)(W_bf + (size_t)w * 8) = v;
    }
    __shared__ int h[NBUCKETS];
    __shared__ int base[NBUCKETS];
    if (t < NBUCKETS) h[t] = 0;
    __syncthreads();
    uint32_t pk[APT]; int bk[APT], rk[APT];
    #pragma unroll
    for (int i = 0; i < APT; ++i) {
        int e = blockIdx.x * AEDGES + i * 1024 + t;
        int d = dst[e];
        int b = d >> BUCKET_BITS;
        bk[i] = b;
        pk[i] = ((uint32_t)(d & (BUCKET_SIZE - 1)) << 20) | ((uint32_t)typ[e] << 17) | (uint32_t)src[e];
        rk[i] = atomicAdd(&h[b], 1);
    }
    __syncthreads();
    if (t < NBUCKETS && h[t] > 0) base[t] = atomicAdd(&bucketCursor[t], h[t]);
    __syncthreads();
    #pragma unroll
    for (int i = 0; i < APT; ++i)
        bins[(size_t)bk[i] * BCAP + base[bk[i]] + rk[i]] = pk[i];
}

// ---------------- A2: per-bucket counting sort + packed CSR offs -------------
// offs[node] = (start << 8) | deg   (start < 196*8960 < 2^24, deg <= ~45)
__global__ __launch_bounds__(1024)
void sortb_kernel(const int* __restrict__ bucketCursor, uint32_t* __restrict__ bins,
                  int* __restrict__ offs) {
    __shared__ int cnt_l[BUCKET_SIZE];
    __shared__ int start_l[BUCKET_SIZE];
    __shared__ int wtot[8];
    const int b = blockIdx.x;
    const int t = threadIdx.x, lane = t & 63, wv = t >> 6;
    const int s = b * BCAP;
    const int cnt = bucketCursor[b];
    if (t < BUCKET_SIZE) cnt_l[t] = 0;
    __syncthreads();
    uint32_t pk[BK]; int rk[BK], ld[BK];
    #pragma unroll
    for (int k = 0; k < BK; ++k) {
        int idx = t + k * 1024;
        ld[k] = -1;
        if (idx < cnt) {
            uint32_t p = bins[s + idx];
            pk[k] = p;
            ld[k] = (int)(p >> 20);
            rk[k] = atomicAdd(&cnt_l[ld[k]], 1);
        }
    }
    __syncthreads();
    int v = 0, x = 0;
    if (t < BUCKET_SIZE) {
        v = cnt_l[t]; x = v;
        #pragma unroll
        for (int d = 1; d < 64; d <<= 1) {
            int tv = __shfl_up(x, d, 64);
            if (lane >= d) x += tv;
        }
        if (lane == 63) wtot[wv] = x;
    }
    __syncthreads();
    if (t == 0) {
        int run = 0;
        #pragma unroll
        for (int j = 0; j < 8; ++j) { int c = wtot[j]; wtot[j] = run; run += c; }
    }
    __syncthreads();
    if (t < BUCKET_SIZE) {
        int excl = x - v + wtot[wv];
        start_l[t] = excl;
        int node = b * BUCKET_SIZE + t;
        if (node < N_NODES) offs[node] = ((s + excl) << 8) | v;
    }
    __syncthreads();
    #pragma unroll
    for (int k = 0; k < BK; ++k)
        if (ld[k] >= 0)
            bins[s + start_l[ld[k]] + rk[k]] = pk[k];
}

// ---------------- transform: R2 champion structure (frozen) ------------------
__global__ __launch_bounds__(512)
void transform_kernel(const float* __restrict__ feat,
                      const unsigned short* __restrict__ W_bf,
                      unsigned short* __restrict__ xw) {
    const int t    = threadIdx.x;
    const int lane = t & 63;
    const int r    = t >> 6;               // wave = relation
    const int quad = lane >> 4;
    const int lrow = lane & 15;

    __shared__ unsigned short sA[2][64 * 136];

    // W-fragments (first operand): rows = channels jm*16+lrow, k-contiguous
    short8 wfr[4][4];
    #pragma unroll
    for (int jm = 0; jm < 4; ++jm)
        #pragma unroll
        for (int kk = 0; kk < 4; ++kk)
            wfr[jm][kk] = *(const short8*)(W_bf +
                ((size_t)r * OUT_FEAT + jm * 16 + lrow) * IN_FEAT + kk * 32 + quad * 8);

    int tile = blockIdx.x;

    // stage first tile into sA[0]
    #pragma unroll
    for (int i = 0; i < 4; ++i) {
        int f4 = t + 512 * i;               // 0..2047
        int row = f4 >> 5, c4 = f4 & 31;
        int n = tile * 64 + row;
        float4 v = (n < N_NODES) ? *(const float4*)(feat + (size_t)n * IN_FEAT + c4 * 4)
                                 : make_float4(0.f, 0.f, 0.f, 0.f);
        uint2 q;
        q.x = cvt_pk_bf16(v.x, v.y);
        q.y = cvt_pk_bf16(v.z, v.w);
        *(uint2*)&sA[0][row * 136 + c4 * 4] = q;
    }

    int p = 0;
    while (tile < NTILES) {
        __syncthreads();                    // sA[p] staged; sA[p^1] fully consumed
        int nxt = tile + TGRID;
        if (nxt < NTILES) {
            #pragma unroll
            for (int i = 0; i < 4; ++i) {
                int f4 = t + 512 * i;
                int row = f4 >> 5, c4 = f4 & 31;
                int n = nxt * 64 + row;
                float4 v = (n < N_NODES) ? *(const float4*)(feat + (size_t)n * IN_FEAT + c4 * 4)
                                         : make_float4(0.f, 0.f, 0.f, 0.f);
                uint2 q;
                q.x = cvt_pk_bf16(v.x, v.y);
                q.y = cvt_pk_bf16(v.z, v.w);
                *(uint2*)&sA[p ^ 1][row * 136 + c4 * 4] = q;
            }
        }

        const int n0 = tile * 64;
        const bool full = (n0 + 64 <= N_NODES);
        #pragma unroll
        for (int nb = 0; nb < 4; ++nb) {
            floatx4 acc[4] = {{0,0,0,0},{0,0,0,0},{0,0,0,0},{0,0,0,0}};
            #pragma unroll
            for (int kk = 0; kk < 4; ++kk) {
                short8 bfrag = *(const short8*)&sA[p][(nb * 16 + lrow) * 136 + kk * 32 + quad * 8];
                #pragma unroll
                for (int jm = 0; jm < 4; ++jm)
                    acc[jm] = __builtin_amdgcn_mfma_f32_16x16x32_bf16(wfr[jm][kk], bfrag, acc[jm], 0, 0, 0);
            }
            int n = n0 + nb * 16 + lrow;
            if (full || n < N_NODES) {
                unsigned short* rowp = xw + ((size_t)r * N_NODES + n) * OUT_FEAT;
                #pragma unroll
                for (int jm = 0; jm < 4; ++jm) {
                    uint2 u;
                    u.x = (uint32_t)f2bf(acc[jm][0]) | ((uint32_t)f2bf(acc[jm][1]) << 16);
                    u.y = (uint32_t)f2bf(acc[jm][2]) | ((uint32_t)f2bf(acc[jm][3]) << 16);
                    *(uint2*)(rowp + jm * 16 + quad * 4) = u;
                }
            }
        }
        p ^= 1;
        tile = nxt;
    }
}

// ---------------- gather: 2 nodes/wave, unrolled inner rounds ----------------
// lane = half*32 + slot*8 + chan; each 32-lane half owns one node, preloads
// 32 packets, 4 edge slots x uint4 (16B) channel loads, 8-round unroll.
__global__ __launch_bounds__(256)
void gather_kernel(const unsigned short* __restrict__ xw, const int* __restrict__ offs,
                   const uint32_t* __restrict__ bins, float* __restrict__ out) {
    const int wv   = threadIdx.x >> 6;
    const int lane = threadIdx.x & 63;
    const int half = lane >> 5;            // which node of the pair
    const int g    = (lane >> 3) & 3;      // edge slot within half
    const int l    = lane & 7;             // channel octet
    const int node = blockIdx.x * 8 + wv * 2 + half;   // grid exact: 100000/8=12500
    const int pd = offs[node];
    const int start = pd >> 8;
    const int deg = pd & 255;
    float acc[8] = {0.f, 0.f, 0.f, 0.f, 0.f, 0.f, 0.f, 0.f};
    for (int base = 0; base < deg; base += 32) {
        int rem = deg - base; if (rem > 32) rem = 32;
        uint32_t pl = bins[start + base + (lane & 31)];   // 32-packet preload (region slack >= ~250)
        #pragma unroll
        for (int i = 0; i < 8; ++i) {
            int ei = i * 4 + g;
            uint32_t p = __shfl(pl, (half << 5) + ei, 64);
            if (ei < rem) {
                int rel = (p >> 17) & 7;
                int src = (int)(p & 0x1FFFF);
                const uint4* q = (const uint4*)(xw + ((size_t)rel * N_NODES + src) * OUT_FEAT + l * 8);
                uint4 u = *q;
                union { uint32_t u; float f; } c;
                c.u = u.x << 16;         acc[0] += c.f;
                c.u = u.x & 0xFFFF0000u; acc[1] += c.f;
                c.u = u.y << 16;         acc[2] += c.f;
                c.u = u.y & 0xFFFF0000u; acc[3] += c.f;
                c.u = u.z << 16;         acc[4] += c.f;
                c.u = u.z & 0xFFFF0000u; acc[5] += c.f;
                c.u = u.w << 16;         acc[6] += c.f;
                c.u = u.w & 0xFFFF0000u; acc[7] += c.f;
            }
        }
    }
    // reduce across the 4 edge slots within each 32-lane half
    #pragma unroll
    for (int d = 8; d < 32; d <<= 1) {
        #pragma unroll
        for (int j = 0; j < 8; ++j)
            acc[j] += __shfl_xor(acc[j], d, 64);
    }
    if (g == 0) {
        float* rowp = out + (size_t)node * OUT_FEAT + l * 8;
        float4 a = make_float4(acc[0], acc[1], acc[2], acc[3]);
        float4 b = make_float4(acc[4], acc[5], acc[6], acc[7]);
        *(float4*)rowp = a;
        *(float4*)(rowp + 4) = b;
    }
}

extern "C" void kernel_launch(void* const* d_in, const int* in_sizes, int n_in,
                              void* d_out, int out_size, void* d_ws, size_t ws_size,
                              hipStream_t stream) {
    const float* feat = (const float*)d_in[0];
    const float* W    = (const float*)d_in[1];
    const int* esrc   = (const int*)d_in[2];
    const int* edst   = (const int*)d_in[3];
    const int* etyp   = (const int*)d_in[4];
    float* out = (float*)d_out;

    // ws layout (~110.0 MB)
    char* ws = (char*)d_ws;
    size_t ofs = 0;
    unsigned short* xw = (unsigned short*)(ws + ofs);
    ofs += (size_t)NUM_RELS * N_NODES * OUT_FEAT * 2;           // 102,400,000
    unsigned short* W_bf = (unsigned short*)(ws + ofs);
    ofs += (size_t)NUM_RELS * OUT_FEAT * IN_FEAT * 2;           // 131,072
    uint32_t* bins = (uint32_t*)(ws + ofs);
    ofs += (size_t)NBUCKETS * BCAP * 4;                         // 7,024,640
    int* offs = (int*)(ws + ofs);
    ofs += ((size_t)N_NODES * 4 + 255) & ~(size_t)255;          // 400,128
    int* bucketCursor = (int*)(ws + ofs); ofs += 1024;

    hipMemsetAsync(bucketCursor, 0, NBUCKETS * sizeof(int), stream);
    bin_kernel<<<ABLOCKS, 1024, 0, stream>>>(esrc, edst, etyp, bucketCursor, bins, W, W_bf);
    sortb_kernel<<<NBUCKETS, 1024, 0, stream>>>(bucketCursor, bins, offs);
    transform_kernel<<<TGRID, 512, 0, stream>>>(feat, W_bf, xw);
    gather_kernel<<<N_NODES / 8, 256, 0, stream>>>(xw, offs, bins, out);
}